// Round 5
// baseline (1746.752 us; speedup 1.0000x reference)
//
#include <hip/hip_runtime.h>
#include <hip/hip_bf16.h>

// B=16, T=2048, D=2048, K(msg)=4, C=128, KC=512, CODEBOOK=512
#define M_BT      32768
#define KC_DIM    512
#define D_DIM     2048
#define C_DIM     128
#define NROWS     131072
#define NCODES    512
#define NELEM     16777216   // NROWS*C_DIM

typedef __bf16 bf16x8 __attribute__((ext_vector_type(8)));
typedef float  f32x4  __attribute__((ext_vector_type(4)));

#define AS3(p) ((__attribute__((address_space(3))) void*)(p))
#define AS1(p) ((const __attribute__((address_space(1))) void*)(p))

static __device__ __forceinline__ ushort f2bf(float x) {
    unsigned u = __float_as_uint(x);
    unsigned r = (u + 0x7fffu + ((u >> 16) & 1u)) >> 16;
    return (ushort)r;
}
static __device__ __forceinline__ float bf2f(ushort u) {
    return __uint_as_float(((unsigned)u) << 16);
}

// ---------------- zero counters ----------------
__global__ __launch_bounds__(512)
void zero_kernel(unsigned* __restrict__ counts, float* __restrict__ loss_sum) {
    counts[threadIdx.x] = 0u;
    if (threadIdx.x == 0) loss_sum[0] = 0.f;
}

// ---------------- numpy-pairwise sum of squares per 128-row ----------------
__global__ __launch_bounds__(256)
void sq_pairwise(const float* __restrict__ src, float* __restrict__ dst, int nrows) {
    int t = threadIdx.x;
    int row = blockIdx.x * 32 + (t >> 3);
    int j = t & 7;
    if (row >= nrows) return;
    const float* p = src + (size_t)row * C_DIM + j;
    float v = p[0];
    float r = __fmul_rn(v, v);
#pragma unroll
    for (int i = 1; i < 16; ++i) {
        float u = p[i * 8];
        r = __fadd_rn(r, __fmul_rn(u, u));
    }
    r = __fadd_rn(r, __shfl_xor(r, 1));
    r = __fadd_rn(r, __shfl_xor(r, 2));
    r = __fadd_rn(r, __shfl_xor(r, 4));
    if (j == 0) dst[row] = r;
}

// ---------------- fp32 GEMM v2: C = A * B^T (+bias), numpy-faithful ----------------
// Both A[M,K] and B[N,K] row-major, k-contiguous. Tiles staged with
// global_load_lds (16B, linear LDS); bank-conflict-free fragment reads via
// source-side XOR chunk swizzle (chunk c of row r stored at c ^ ((r>>3)&7)).
// Per-output-element arithmetic: sequential-k fmaf chain with CHUNK-sized
// fold blocks — bit-identical to the validated r3 kernel.
template<int EPI, int DO_BIAS, int CHUNK>
__global__ __launch_bounds__(256, 2)
void gemm_nt2(const float* __restrict__ A, const float* __restrict__ B,
              const float* __restrict__ bias, float* __restrict__ C,
              int M, int N, int K,
              const float* __restrict__ xsq, const float* __restrict__ esq,
              float* __restrict__ pmin, int* __restrict__ pidx)
{
    __shared__ float As[4096];   // [128 rows][32 k] linear, chunk-swizzled
    __shared__ float Bs[4096];
    const int tid  = threadIdx.x;
    const int ty   = tid >> 4, tx = tid & 15;
    const int lane = tid & 63, wave = tid >> 6;
    const int row0 = blockIdx.x * 128, col0 = blockIdx.y * 128;

    float acc[8][8];
    float accC[8][8];
#pragma unroll
    for (int i = 0; i < 8; ++i)
#pragma unroll
        for (int j = 0; j < 8; ++j) { acc[i][j] = 0.f; accC[i][j] = 0.f; }

    // staging addresses: slot s = g*64+lane, row r = g*8+(lane>>3),
    // source chunk c = (lane&7) ^ (g&7)
    size_t aoff[4], boff[4];
    int lb[4];
#pragma unroll
    for (int rr = 0; rr < 4; ++rr) {
        const int g = wave * 4 + rr;
        const int r = g * 8 + (lane >> 3);
        const int c = (lane & 7) ^ (g & 7);
        aoff[rr] = (size_t)(row0 + r) * K + c * 4;
        boff[rr] = (size_t)(col0 + r) * K + c * 4;
        lb[rr]   = g * 256;
    }

    const int sa = ty & 7, sb = tx & 7;

    for (int k0 = 0; k0 < K; k0 += 32) {
#pragma unroll
        for (int rr = 0; rr < 4; ++rr) {
            __builtin_amdgcn_global_load_lds(AS1(A + aoff[rr] + k0), AS3(As + lb[rr]), 16, 0, 0);
            __builtin_amdgcn_global_load_lds(AS1(B + boff[rr] + k0), AS3(Bs + lb[rr]), 16, 0, 0);
        }
        __syncthreads();

#pragma unroll
        for (int kk = 0; kk < 8; ++kk) {
            float4 a4[8], b4[8];
#pragma unroll
            for (int i = 0; i < 8; ++i)
                a4[i] = *(const float4*)&As[(ty * 8 + i) * 32 + ((kk ^ sa) << 2)];
#pragma unroll
            for (int j = 0; j < 8; ++j)
                b4[j] = *(const float4*)&Bs[(tx * 8 + j) * 32 + ((kk ^ sb) << 2)];
            if constexpr (CHUNK > 0) {
#pragma unroll
                for (int i = 0; i < 8; ++i)
#pragma unroll
                    for (int j = 0; j < 8; ++j) {
                        float t = accC[i][j];
                        t = fmaf(a4[i].x, b4[j].x, t);
                        t = fmaf(a4[i].y, b4[j].y, t);
                        t = fmaf(a4[i].z, b4[j].z, t);
                        t = fmaf(a4[i].w, b4[j].w, t);
                        accC[i][j] = t;
                    }
            } else {
#pragma unroll
                for (int i = 0; i < 8; ++i)
#pragma unroll
                    for (int j = 0; j < 8; ++j) {
                        float t = acc[i][j];
                        t = fmaf(a4[i].x, b4[j].x, t);
                        t = fmaf(a4[i].y, b4[j].y, t);
                        t = fmaf(a4[i].z, b4[j].z, t);
                        t = fmaf(a4[i].w, b4[j].w, t);
                        acc[i][j] = t;
                    }
            }
        }
        __syncthreads();

        if constexpr (CHUNK > 0) {
            if (((k0 + 32) % CHUNK) == 0) {
#pragma unroll
                for (int i = 0; i < 8; ++i)
#pragma unroll
                    for (int j = 0; j < 8; ++j) {
                        acc[i][j] = __fadd_rn(acc[i][j], accC[i][j]);
                        accC[i][j] = 0.f;
                    }
            }
        }
    }
    if constexpr (CHUNK > 0) {
        if ((K % CHUNK) != 0) {
#pragma unroll
            for (int i = 0; i < 8; ++i)
#pragma unroll
                for (int j = 0; j < 8; ++j)
                    acc[i][j] = __fadd_rn(acc[i][j], accC[i][j]);
        }
    }

    if constexpr (EPI == 0) {
        float bv[8];
#pragma unroll
        for (int j = 0; j < 8; ++j) bv[j] = DO_BIAS ? bias[col0 + tx * 8 + j] : 0.f;
#pragma unroll
        for (int i = 0; i < 8; ++i) {
            size_t r = (size_t)(row0 + ty * 8 + i) * N + col0 + tx * 8;
            float4 o0, o1;
            o0.x = __fadd_rn(acc[i][0], bv[0]); o0.y = __fadd_rn(acc[i][1], bv[1]);
            o0.z = __fadd_rn(acc[i][2], bv[2]); o0.w = __fadd_rn(acc[i][3], bv[3]);
            o1.x = __fadd_rn(acc[i][4], bv[4]); o1.y = __fadd_rn(acc[i][5], bv[5]);
            o1.z = __fadd_rn(acc[i][6], bv[6]); o1.w = __fadd_rn(acc[i][7], bv[7]);
            *(float4*)(C + r) = o0;
            *(float4*)(C + r + 4) = o1;
        }
    } else {
        // dist epilogue; reuse As/Bs LDS (all tile reads drained by last barrier)
        float (*rmin)[16] = (float (*)[16])As;
        int   (*ridx)[16] = (int (*)[16])Bs;
        float es[8];
#pragma unroll
        for (int j = 0; j < 8; ++j) es[j] = esq[col0 + tx * 8 + j];
#pragma unroll
        for (int i = 0; i < 8; ++i) {
            float xs = xsq[row0 + ty * 8 + i];
            float b = __fadd_rn(__fsub_rn(xs, __fmul_rn(2.0f, acc[i][0])), es[0]);
            int bi = col0 + tx * 8;
#pragma unroll
            for (int j = 1; j < 8; ++j) {
                float d = __fadd_rn(__fsub_rn(xs, __fmul_rn(2.0f, acc[i][j])), es[j]);
                if (d < b) { b = d; bi = col0 + tx * 8 + j; }
            }
            rmin[ty * 8 + i][tx] = b;
            ridx[ty * 8 + i][tx] = bi;
        }
        __syncthreads();
        if (tid < 128) {
            float b = rmin[tid][0]; int ix = ridx[tid][0];
#pragma unroll
            for (int t = 1; t < 16; ++t) {
                if (rmin[tid][t] < b) { b = rmin[tid][t]; ix = ridx[tid][t]; }
            }
            size_t o = (size_t)(row0 + tid) * gridDim.y + blockIdx.y;
            pmin[o] = b; pidx[o] = ix;
        }
    }
}

// ---------------- merge 4 col-blocks -> final idx + histogram ----------------
__global__ __launch_bounds__(256)
void finalize_idx(const float* __restrict__ pmin, const int* __restrict__ pidx,
                  int* __restrict__ idx_int, float* __restrict__ idx_f,
                  unsigned* __restrict__ counts) {
    __shared__ unsigned hist[NCODES];
    int t = threadIdx.x;
    hist[t] = 0u; hist[t + 256] = 0u;
    __syncthreads();
    int row = blockIdx.x * 256 + t;
    size_t base = (size_t)row * 4;
    float b = pmin[base]; int ix = pidx[base];
#pragma unroll
    for (int nb = 1; nb < 4; ++nb) {
        float v = pmin[base + nb];
        if (v < b) { b = v; ix = pidx[base + nb]; }
    }
    idx_int[row] = ix;
    idx_f[row] = (float)ix;
    atomicAdd(&hist[ix], 1u);
    __syncthreads();
    if (hist[t]) atomicAdd(&counts[t], hist[t]);
    if (hist[t + 256]) atomicAdd(&counts[t + 256], hist[t + 256]);
}

// ---------------- split codebook / dec_w into bf16 hi+lo ----------------
__global__ __launch_bounds__(256)
void split_hi_lo(const float* __restrict__ src, ushort* __restrict__ hi,
                 ushort* __restrict__ lo, int n4) {
    int e = blockIdx.x * 256 + threadIdx.x;
    if (e >= n4) return;
    float4 v = *(const float4*)&src[(size_t)e * 4];
    ushort h0 = f2bf(v.x), h1 = f2bf(v.y), h2 = f2bf(v.z), h3 = f2bf(v.w);
    ushort l0 = f2bf(v.x - bf2f(h0)), l1 = f2bf(v.y - bf2f(h1));
    ushort l2 = f2bf(v.z - bf2f(h2)), l3 = f2bf(v.w - bf2f(h3));
    ushort4 H; H.x = h0; H.y = h1; H.z = h2; H.w = h3;
    ushort4 L; L.x = l0; L.y = l1; L.z = l2; L.w = l3;
    *(ushort4*)&hi[(size_t)e * 4] = H;
    *(ushort4*)&lo[(size_t)e * 4] = L;
}

// ---------------- loss only (reads flat, does NOT modify it) ----------------
__global__ __launch_bounds__(256)
void gather_loss(const float* __restrict__ flat, const int* __restrict__ idx,
                 const float* __restrict__ cb, float* __restrict__ loss_sum) {
    size_t e0 = ((size_t)blockIdx.x * 256 + threadIdx.x) * 8;
    int n = (int)(e0 >> 7);
    int c = (int)(e0 & 127);
    int k = idx[n];
    const float4* qp = (const float4*)(cb + (size_t)k * C_DIM + c);
    float4 q0 = qp[0], q1 = qp[1];
    const float4* fp = (const float4*)(flat + e0);
    float4 f0 = fp[0], f1 = fp[1];
    float s = 0.f, d;
    d = q0.x - f0.x; s += d * d;  d = q0.y - f0.y; s += d * d;
    d = q0.z - f0.z; s += d * d;  d = q0.w - f0.w; s += d * d;
    d = q1.x - f1.x; s += d * d;  d = q1.y - f1.y; s += d * d;
    d = q1.z - f1.z; s += d * d;  d = q1.w - f1.w; s += d * d;

    __shared__ float redf[256];
    redf[threadIdx.x] = s;
    __syncthreads();
    for (int st = 128; st; st >>= 1) {
        if (threadIdx.x < st) redf[threadIdx.x] += redf[threadIdx.x + st];
        __syncthreads();
    }
    if (threadIdx.x == 0) atomicAdd(loss_sum, redf[0]);
}

// ---------------- gather split-bf16 quantized rows ----------------
__global__ __launch_bounds__(256)
void build_q(const int* __restrict__ idx, const ushort* __restrict__ cbh,
             const ushort* __restrict__ cbl, ushort* __restrict__ Qh,
             ushort* __restrict__ Ql) {
    int t = blockIdx.x * 256 + threadIdx.x;   // 16B chunk id
    int n = t >> 4, c8 = t & 15;
    int k = idx[n];
    uint4 vh = *(const uint4*)&cbh[(size_t)k * C_DIM + c8 * 8];
    uint4 vl = *(const uint4*)&cbl[(size_t)k * C_DIM + c8 * 8];
    *(uint4*)&Qh[(size_t)n * C_DIM + c8 * 8] = vh;
    *(uint4*)&Ql[(size_t)n * C_DIM + c8 * 8] = vl;
}

// ---------------- decoder: split-bf16 MFMA GEMM ----------------
__global__ __launch_bounds__(256)
void dec_gemm_bf16(const ushort* __restrict__ Qh, const ushort* __restrict__ Ql,
                   const ushort* __restrict__ Wh, const ushort* __restrict__ Wl,
                   const float* __restrict__ bias, float* __restrict__ C)
{
    constexpr int Kd = 512, Nd = 2048;
    __shared__ ushort Ah[128 * 32], Al[128 * 32], Bh[128 * 32], Bl[128 * 32];
    const int tid  = threadIdx.x;
    const int lane = tid & 63, wave = tid >> 6;
    const int wm = wave >> 1, wn = wave & 1;
    const int row0 = blockIdx.x * 128, col0 = blockIdx.y * 128;

    f32x4 acc[4][4];
#pragma unroll
    for (int i = 0; i < 4; ++i)
#pragma unroll
        for (int j = 0; j < 4; ++j)
#pragma unroll
            for (int q = 0; q < 4; ++q) acc[i][j][q] = 0.f;

    const int fr = lane & 15, s4 = lane >> 4;

    for (int kt = 0; kt < Kd / 32; ++kt) {
        const int k0 = kt * 32;
#pragma unroll
        for (int r = 0; r < 2; ++r) {
            const int t2 = r * 256 + wave * 64 + lane;
            const int ro = t2 >> 2, sb = t2 & 3;
            const int base = (r * 256 + wave * 64) * 8;
            const size_t ga = (size_t)(row0 + ro) * Kd + k0 + sb * 8;
            const size_t gb = (size_t)(col0 + ro) * Kd + k0 + sb * 8;
            __builtin_amdgcn_global_load_lds(AS1(Qh + ga), AS3(&Ah[base]), 16, 0, 0);
            __builtin_amdgcn_global_load_lds(AS1(Ql + ga), AS3(&Al[base]), 16, 0, 0);
            __builtin_amdgcn_global_load_lds(AS1(Wh + gb), AS3(&Bh[base]), 16, 0, 0);
            __builtin_amdgcn_global_load_lds(AS1(Wl + gb), AS3(&Bl[base]), 16, 0, 0);
        }
        __syncthreads();

        bf16x8 ah[4], al[4], bh[4], bl[4];
#pragma unroll
        for (int mi = 0; mi < 4; ++mi) {
            const int off = (wm * 64 + mi * 16 + fr) * 32 + s4 * 8;
            ah[mi] = *(const bf16x8*)&Ah[off];
            al[mi] = *(const bf16x8*)&Al[off];
        }
#pragma unroll
        for (int ni = 0; ni < 4; ++ni) {
            const int off = (wn * 64 + ni * 16 + fr) * 32 + s4 * 8;
            bh[ni] = *(const bf16x8*)&Bh[off];
            bl[ni] = *(const bf16x8*)&Bl[off];
        }
#pragma unroll
        for (int mi = 0; mi < 4; ++mi)
#pragma unroll
            for (int ni = 0; ni < 4; ++ni) {
                acc[mi][ni] = __builtin_amdgcn_mfma_f32_16x16x32_bf16(ah[mi], bh[ni], acc[mi][ni], 0, 0, 0);
                acc[mi][ni] = __builtin_amdgcn_mfma_f32_16x16x32_bf16(ah[mi], bl[ni], acc[mi][ni], 0, 0, 0);
                acc[mi][ni] = __builtin_amdgcn_mfma_f32_16x16x32_bf16(al[mi], bh[ni], acc[mi][ni], 0, 0, 0);
            }
        __syncthreads();
    }

#pragma unroll
    for (int ni = 0; ni < 4; ++ni) {
        const int c = col0 + wn * 64 + ni * 16 + fr;
        const float bv = bias[c];
#pragma unroll
        for (int mi = 0; mi < 4; ++mi) {
            const int r = row0 + wm * 64 + mi * 16 + s4 * 4;
#pragma unroll
            for (int q = 0; q < 4; ++q)
                C[(size_t)(r + q) * Nd + c] = acc[mi][ni][q] + bv;
        }
    }
}

// ---------------- scalars ----------------
__global__ __launch_bounds__(512)
void finalize_scalars(const unsigned* __restrict__ counts,
                      const float* __restrict__ loss_sum, float* __restrict__ out5) {
    __shared__ float rent[512];
    __shared__ float ruse[512];
    int t = threadIdx.x;
    float c = (float)counts[t];
    float avg = c * (1.0f / (float)NROWS);
    rent[t] = avg * logf(avg + 1e-10f);
    ruse[t] = counts[t] > 0u ? 1.f : 0.f;
    __syncthreads();
    for (int st = 256; st; st >>= 1) {
        if (t < st) { rent[t] += rent[t + st]; ruse[t] += ruse[t + st]; }
        __syncthreads();
    }
    if (t == 0) {
        float H = -rent[0];
        float perp = expf(H);
        float cl = loss_sum[0] * (1.0f / (float)NELEM);
        out5[0] = cl + 0.25f * cl;
        out5[1] = cl;
        out5[2] = cl;
        out5[3] = perp;
        out5[4] = ruse[0] * (1.0f / (float)NCODES);
    }
}

extern "C" void kernel_launch(void* const* d_in, const int* in_sizes, int n_in,
                              void* d_out, int out_size, void* d_ws, size_t ws_size,
                              hipStream_t stream) {
    const float* h     = (const float*)d_in[0];
    const float* enc_w = (const float*)d_in[1];
    const float* enc_b = (const float*)d_in[2];
    const float* cb    = (const float*)d_in[3];
    const float* dec_w = (const float*)d_in[4];
    const float* dec_b = (const float*)d_in[5];
    float* out = (float*)d_out;

    float* ws = (float*)d_ws;
    float*    flat     = ws;                         // [0, 16777216)
    float*    xsq      = ws + 16777216;              // 131072 (dead after dist)
    float*    pmin     = ws + 16908288;              // 524288 (dead after finalize)
    int*      pidx     = (int*)(ws + 17432576);      // 524288 (dead after finalize)
    int*      idx_int  = (int*)(ws + 17956864);      // 131072
    float*    esq      = ws + 18087936;              // 512
    unsigned* counts   = (unsigned*)(ws + 18088448); // 512
    float*    loss_sum = ws + 18088960;              // 1

    // overlays (used only after their hosts are dead):
    ushort* Qh  = (ushort*)ws;                       // over flat
    ushort* Ql  = (ushort*)(ws + 8388608);           // over flat
    ushort* cbh = (ushort*)(ws + 16777216);          // over xsq
    ushort* cbl = (ushort*)(ws + 16809984);          // over xsq
    ushort* Wh  = (ushort*)(ws + 16842752);          // over xsq/pmin
    ushort* Wl  = (ushort*)(ws + 17367040);          // over pmin/pidx

    float* msg_out = out;                     // 67108864
    float* idx_out = out + 67108864;          // 131072
    float* sc_out  = out + 67108864 + 131072; // 5

    zero_kernel<<<1, 512, 0, stream>>>(counts, loss_sum);
    sq_pairwise<<<NCODES / 32, 256, 0, stream>>>(cb, esq, NCODES);

    // encoder: flat = h @ enc_w^T + enc_b (numpy kc=384 folds), DMA-staged
    gemm_nt2<0, 1, 384><<<dim3(M_BT / 128, KC_DIM / 128), 256, 0, stream>>>(
        h, enc_w, enc_b, flat, M_BT, KC_DIM, D_DIM, nullptr, nullptr, nullptr, nullptr);

    sq_pairwise<<<NROWS / 32, 256, 0, stream>>>(flat, xsq, NROWS);

    // distances + per-colblock argmin
    gemm_nt2<1, 0, 0><<<dim3(NROWS / 128, NCODES / 128), 256, 0, stream>>>(
        flat, cb, nullptr, nullptr, NROWS, NCODES, C_DIM, xsq, esq, pmin, pidx);

    finalize_idx<<<NROWS / 256, 256, 0, stream>>>(pmin, pidx, idx_int, idx_out, counts);

    // xsq/pmin/pidx now dead -> build bf16 splits in their space
    split_hi_lo<<<(NCODES * C_DIM / 4 + 255) / 256, 256, 0, stream>>>(cb, cbh, cbl, NCODES * C_DIM / 4);
    split_hi_lo<<<(D_DIM * KC_DIM / 4 + 255) / 256, 256, 0, stream>>>(dec_w, Wh, Wl, D_DIM * KC_DIM / 4);

    gather_loss<<<NELEM / (256 * 8), 256, 0, stream>>>(flat, idx_int, cb, loss_sum);

    // flat now dead -> gather split-bf16 quantized rows into its space
    build_q<<<NROWS * 16 / 256, 256, 0, stream>>>(idx_int, cbh, cbl, Qh, Ql);

    // decoder on matrix cores
    dec_gemm_bf16<<<dim3(M_BT / 128, D_DIM / 128), 256, 0, stream>>>(
        Qh, Ql, Wh, Wl, dec_b, msg_out);

    finalize_scalars<<<1, 512, 0, stream>>>(counts, loss_sum, sc_out);
}

// Round 6
// 1724.975 us; speedup vs baseline: 1.0126x; 1.0126x over previous
//
#include <hip/hip_runtime.h>
#include <hip/hip_bf16.h>

// B=16, T=2048, D=2048, K(msg)=4, C=128, KC=512, CODEBOOK=512
#define M_BT      32768
#define KC_DIM    512
#define D_DIM     2048
#define C_DIM     128
#define NROWS     131072
#define NCODES    512
#define NELEM     16777216   // NROWS*C_DIM

typedef __bf16 bf16x8 __attribute__((ext_vector_type(8)));
typedef float  f32x4  __attribute__((ext_vector_type(4)));

#define AS3(p) ((__attribute__((address_space(3))) void*)(p))
#define AS1(p) ((const __attribute__((address_space(1))) void*)(p))

static __device__ __forceinline__ ushort f2bf(float x) {
    unsigned u = __float_as_uint(x);
    unsigned r = (u + 0x7fffu + ((u >> 16) & 1u)) >> 16;
    return (ushort)r;
}
static __device__ __forceinline__ float bf2f(ushort u) {
    return __uint_as_float(((unsigned)u) << 16);
}

// ---------------- zero counters ----------------
__global__ __launch_bounds__(512)
void zero_kernel(unsigned* __restrict__ counts, float* __restrict__ loss_sum) {
    counts[threadIdx.x] = 0u;
    if (threadIdx.x == 0) loss_sum[0] = 0.f;
}

// ---------------- numpy-pairwise sum of squares per 128-row ----------------
__global__ __launch_bounds__(256)
void sq_pairwise(const float* __restrict__ src, float* __restrict__ dst, int nrows) {
    int t = threadIdx.x;
    int row = blockIdx.x * 32 + (t >> 3);
    int j = t & 7;
    if (row >= nrows) return;
    const float* p = src + (size_t)row * C_DIM + j;
    float v = p[0];
    float r = __fmul_rn(v, v);
#pragma unroll
    for (int i = 1; i < 16; ++i) {
        float u = p[i * 8];
        r = __fadd_rn(r, __fmul_rn(u, u));
    }
    r = __fadd_rn(r, __shfl_xor(r, 1));
    r = __fadd_rn(r, __shfl_xor(r, 2));
    r = __fadd_rn(r, __shfl_xor(r, 4));
    if (j == 0) dst[row] = r;
}

// ---------------- fp32 GEMM v2: C = A * B^T (+bias), numpy-faithful ----------------
// blockIdx.x = col-block (fast: co-resident blocks share the A-tile),
// blockIdx.y = row-block. Tiles staged with global_load_lds (16B, linear LDS);
// conflict-free fragment reads via source-side XOR chunk swizzle.
// Per-output-element arithmetic: sequential-k fmaf chain with CHUNK folds —
// bit-identical to the validated r3/r4 kernels.
template<int EPI, int DO_BIAS, int CHUNK>
__global__ __launch_bounds__(256)
void gemm_nt2(const float* __restrict__ A, const float* __restrict__ B,
              const float* __restrict__ bias, float* __restrict__ C,
              int M, int N, int K,
              const float* __restrict__ xsq, const float* __restrict__ esq,
              float* __restrict__ pmin, int* __restrict__ pidx)
{
    __shared__ float As[4096];   // [128 rows][32 k] linear, chunk-swizzled
    __shared__ float Bs[4096];
    const int tid  = threadIdx.x;
    const int ty   = tid >> 4, tx = tid & 15;
    const int lane = tid & 63, wave = tid >> 6;
    const int row0 = blockIdx.y * 128, col0 = blockIdx.x * 128;

    float acc[8][8];
    float accC[8][8];
#pragma unroll
    for (int i = 0; i < 8; ++i)
#pragma unroll
        for (int j = 0; j < 8; ++j) { acc[i][j] = 0.f; accC[i][j] = 0.f; }

    // staging: slot s = g*64+lane, row r = g*8+(lane>>3), src chunk c=(lane&7)^(g&7)
    size_t aoff[4], boff[4];
    int lb[4];
#pragma unroll
    for (int rr = 0; rr < 4; ++rr) {
        const int g = wave * 4 + rr;
        const int r = g * 8 + (lane >> 3);
        const int c = (lane & 7) ^ (g & 7);
        aoff[rr] = (size_t)(row0 + r) * K + c * 4;
        boff[rr] = (size_t)(col0 + r) * K + c * 4;
        lb[rr]   = g * 256;
    }

    const int sa = ty & 7, sb = tx & 7;

    for (int k0 = 0; k0 < K; k0 += 32) {
#pragma unroll
        for (int rr = 0; rr < 4; ++rr) {
            __builtin_amdgcn_global_load_lds(AS1(A + aoff[rr] + k0), AS3(As + lb[rr]), 16, 0, 0);
            __builtin_amdgcn_global_load_lds(AS1(B + boff[rr] + k0), AS3(Bs + lb[rr]), 16, 0, 0);
        }
        __syncthreads();

#pragma unroll
        for (int kk = 0; kk < 8; ++kk) {
            float4 b4[8];
#pragma unroll
            for (int j = 0; j < 8; ++j)
                b4[j] = *(const float4*)&Bs[(tx * 8 + j) * 32 + ((kk ^ sb) << 2)];
            if constexpr (CHUNK > 0) {
#pragma unroll
                for (int i = 0; i < 8; ++i) {
                    float4 a4 = *(const float4*)&As[(ty * 8 + i) * 32 + ((kk ^ sa) << 2)];
#pragma unroll
                    for (int j = 0; j < 8; ++j) {
                        float t = accC[i][j];
                        t = fmaf(a4.x, b4[j].x, t);
                        t = fmaf(a4.y, b4[j].y, t);
                        t = fmaf(a4.z, b4[j].z, t);
                        t = fmaf(a4.w, b4[j].w, t);
                        accC[i][j] = t;
                    }
                }
            } else {
#pragma unroll
                for (int i = 0; i < 8; ++i) {
                    float4 a4 = *(const float4*)&As[(ty * 8 + i) * 32 + ((kk ^ sa) << 2)];
#pragma unroll
                    for (int j = 0; j < 8; ++j) {
                        float t = acc[i][j];
                        t = fmaf(a4.x, b4[j].x, t);
                        t = fmaf(a4.y, b4[j].y, t);
                        t = fmaf(a4.z, b4[j].z, t);
                        t = fmaf(a4.w, b4[j].w, t);
                        acc[i][j] = t;
                    }
                }
            }
        }
        __syncthreads();

        if constexpr (CHUNK > 0) {
            if (((k0 + 32) % CHUNK) == 0) {
#pragma unroll
                for (int i = 0; i < 8; ++i)
#pragma unroll
                    for (int j = 0; j < 8; ++j) {
                        acc[i][j] = __fadd_rn(acc[i][j], accC[i][j]);
                        accC[i][j] = 0.f;
                    }
            }
        }
    }
    if constexpr (CHUNK > 0) {
        if ((K % CHUNK) != 0) {
#pragma unroll
            for (int i = 0; i < 8; ++i)
#pragma unroll
                for (int j = 0; j < 8; ++j)
                    acc[i][j] = __fadd_rn(acc[i][j], accC[i][j]);
        }
    }

    if constexpr (EPI == 0) {
        float bv[8];
#pragma unroll
        for (int j = 0; j < 8; ++j) bv[j] = DO_BIAS ? bias[col0 + tx * 8 + j] : 0.f;
#pragma unroll
        for (int i = 0; i < 8; ++i) {
            size_t r = (size_t)(row0 + ty * 8 + i) * N + col0 + tx * 8;
            float4 o0, o1;
            o0.x = __fadd_rn(acc[i][0], bv[0]); o0.y = __fadd_rn(acc[i][1], bv[1]);
            o0.z = __fadd_rn(acc[i][2], bv[2]); o0.w = __fadd_rn(acc[i][3], bv[3]);
            o1.x = __fadd_rn(acc[i][4], bv[4]); o1.y = __fadd_rn(acc[i][5], bv[5]);
            o1.z = __fadd_rn(acc[i][6], bv[6]); o1.w = __fadd_rn(acc[i][7], bv[7]);
            *(float4*)(C + r) = o0;
            *(float4*)(C + r + 4) = o1;
        }
    } else {
        // dist epilogue; reuse As/Bs LDS (tile reads drained by last barrier)
        float (*rmin)[16] = (float (*)[16])As;
        int   (*ridx)[16] = (int (*)[16])Bs;
        float es[8];
#pragma unroll
        for (int j = 0; j < 8; ++j) es[j] = esq[col0 + tx * 8 + j];
#pragma unroll
        for (int i = 0; i < 8; ++i) {
            float xs = xsq[row0 + ty * 8 + i];
            float b = __fadd_rn(__fsub_rn(xs, __fmul_rn(2.0f, acc[i][0])), es[0]);
            int bi = col0 + tx * 8;
#pragma unroll
            for (int j = 1; j < 8; ++j) {
                float d = __fadd_rn(__fsub_rn(xs, __fmul_rn(2.0f, acc[i][j])), es[j]);
                if (d < b) { b = d; bi = col0 + tx * 8 + j; }
            }
            rmin[ty * 8 + i][tx] = b;
            ridx[ty * 8 + i][tx] = bi;
        }
        __syncthreads();
        if (tid < 128) {
            float b = rmin[tid][0]; int ix = ridx[tid][0];
#pragma unroll
            for (int t = 1; t < 16; ++t) {
                if (rmin[tid][t] < b) { b = rmin[tid][t]; ix = ridx[tid][t]; }
            }
            size_t o = (size_t)(row0 + tid) * gridDim.x + blockIdx.x;
            pmin[o] = b; pidx[o] = ix;
        }
    }
}

// ---------------- merge 4 col-blocks -> final idx + histogram ----------------
__global__ __launch_bounds__(256)
void finalize_idx(const float* __restrict__ pmin, const int* __restrict__ pidx,
                  int* __restrict__ idx_int, float* __restrict__ idx_f,
                  unsigned* __restrict__ counts) {
    __shared__ unsigned hist[NCODES];
    int t = threadIdx.x;
    hist[t] = 0u; hist[t + 256] = 0u;
    __syncthreads();
    int row = blockIdx.x * 256 + t;
    size_t base = (size_t)row * 4;
    float b = pmin[base]; int ix = pidx[base];
#pragma unroll
    for (int nb = 1; nb < 4; ++nb) {
        float v = pmin[base + nb];
        if (v < b) { b = v; ix = pidx[base + nb]; }
    }
    idx_int[row] = ix;
    idx_f[row] = (float)ix;
    atomicAdd(&hist[ix], 1u);
    __syncthreads();
    if (hist[t]) atomicAdd(&counts[t], hist[t]);
    if (hist[t + 256]) atomicAdd(&counts[t + 256], hist[t + 256]);
}

// ---------------- split codebook / dec_w into bf16 hi+lo ----------------
__global__ __launch_bounds__(256)
void split_hi_lo(const float* __restrict__ src, ushort* __restrict__ hi,
                 ushort* __restrict__ lo, int n4) {
    int e = blockIdx.x * 256 + threadIdx.x;
    if (e >= n4) return;
    float4 v = *(const float4*)&src[(size_t)e * 4];
    ushort h0 = f2bf(v.x), h1 = f2bf(v.y), h2 = f2bf(v.z), h3 = f2bf(v.w);
    ushort l0 = f2bf(v.x - bf2f(h0)), l1 = f2bf(v.y - bf2f(h1));
    ushort l2 = f2bf(v.z - bf2f(h2)), l3 = f2bf(v.w - bf2f(h3));
    ushort4 H; H.x = h0; H.y = h1; H.z = h2; H.w = h3;
    ushort4 L; L.x = l0; L.y = l1; L.z = l2; L.w = l3;
    *(ushort4*)&hi[(size_t)e * 4] = H;
    *(ushort4*)&lo[(size_t)e * 4] = L;
}

// ---------------- loss only (reads flat, does NOT modify it) ----------------
__global__ __launch_bounds__(256)
void gather_loss(const float* __restrict__ flat, const int* __restrict__ idx,
                 const float* __restrict__ cb, float* __restrict__ loss_sum) {
    size_t e0 = ((size_t)blockIdx.x * 256 + threadIdx.x) * 8;
    int n = (int)(e0 >> 7);
    int c = (int)(e0 & 127);
    int k = idx[n];
    const float4* qp = (const float4*)(cb + (size_t)k * C_DIM + c);
    float4 q0 = qp[0], q1 = qp[1];
    const float4* fp = (const float4*)(flat + e0);
    float4 f0 = fp[0], f1 = fp[1];
    float s = 0.f, d;
    d = q0.x - f0.x; s += d * d;  d = q0.y - f0.y; s += d * d;
    d = q0.z - f0.z; s += d * d;  d = q0.w - f0.w; s += d * d;
    d = q1.x - f1.x; s += d * d;  d = q1.y - f1.y; s += d * d;
    d = q1.z - f1.z; s += d * d;  d = q1.w - f1.w; s += d * d;

    __shared__ float redf[256];
    redf[threadIdx.x] = s;
    __syncthreads();
    for (int st = 128; st; st >>= 1) {
        if (threadIdx.x < st) redf[threadIdx.x] += redf[threadIdx.x + st];
        __syncthreads();
    }
    if (threadIdx.x == 0) atomicAdd(loss_sum, redf[0]);
}

// ---------------- gather split-bf16 quantized rows ----------------
__global__ __launch_bounds__(256)
void build_q(const int* __restrict__ idx, const ushort* __restrict__ cbh,
             const ushort* __restrict__ cbl, ushort* __restrict__ Qh,
             ushort* __restrict__ Ql) {
    int t = blockIdx.x * 256 + threadIdx.x;   // 16B chunk id
    int n = t >> 4, c8 = t & 15;
    int k = idx[n];
    uint4 vh = *(const uint4*)&cbh[(size_t)k * C_DIM + c8 * 8];
    uint4 vl = *(const uint4*)&cbl[(size_t)k * C_DIM + c8 * 8];
    *(uint4*)&Qh[(size_t)n * C_DIM + c8 * 8] = vh;
    *(uint4*)&Ql[(size_t)n * C_DIM + c8 * 8] = vl;
}

// ---------------- decoder: split-bf16 MFMA GEMM ----------------
// blockIdx.x = col-block (fast), blockIdx.y = row-block.
__global__ __launch_bounds__(256)
void dec_gemm_bf16(const ushort* __restrict__ Qh, const ushort* __restrict__ Ql,
                   const ushort* __restrict__ Wh, const ushort* __restrict__ Wl,
                   const float* __restrict__ bias, float* __restrict__ C)
{
    constexpr int Kd = 512, Nd = 2048;
    __shared__ ushort Ah[128 * 32], Al[128 * 32], Bh[128 * 32], Bl[128 * 32];
    const int tid  = threadIdx.x;
    const int lane = tid & 63, wave = tid >> 6;
    const int wm = wave >> 1, wn = wave & 1;
    const int row0 = blockIdx.y * 128, col0 = blockIdx.x * 128;

    f32x4 acc[4][4];
#pragma unroll
    for (int i = 0; i < 4; ++i)
#pragma unroll
        for (int j = 0; j < 4; ++j)
#pragma unroll
            for (int q = 0; q < 4; ++q) acc[i][j][q] = 0.f;

    const int fr = lane & 15, s4 = lane >> 4;

    for (int kt = 0; kt < Kd / 32; ++kt) {
        const int k0 = kt * 32;
#pragma unroll
        for (int r = 0; r < 2; ++r) {
            const int t2 = r * 256 + wave * 64 + lane;
            const int ro = t2 >> 2, sb = t2 & 3;
            const int base = (r * 256 + wave * 64) * 8;
            const size_t ga = (size_t)(row0 + ro) * Kd + k0 + sb * 8;
            const size_t gb = (size_t)(col0 + ro) * Kd + k0 + sb * 8;
            __builtin_amdgcn_global_load_lds(AS1(Qh + ga), AS3(&Ah[base]), 16, 0, 0);
            __builtin_amdgcn_global_load_lds(AS1(Ql + ga), AS3(&Al[base]), 16, 0, 0);
            __builtin_amdgcn_global_load_lds(AS1(Wh + gb), AS3(&Bh[base]), 16, 0, 0);
            __builtin_amdgcn_global_load_lds(AS1(Wl + gb), AS3(&Bl[base]), 16, 0, 0);
        }
        __syncthreads();

        bf16x8 ah[4], al[4], bh[4], bl[4];
#pragma unroll
        for (int mi = 0; mi < 4; ++mi) {
            const int off = (wm * 64 + mi * 16 + fr) * 32 + s4 * 8;
            ah[mi] = *(const bf16x8*)&Ah[off];
            al[mi] = *(const bf16x8*)&Al[off];
        }
#pragma unroll
        for (int ni = 0; ni < 4; ++ni) {
            const int off = (wn * 64 + ni * 16 + fr) * 32 + s4 * 8;
            bh[ni] = *(const bf16x8*)&Bh[off];
            bl[ni] = *(const bf16x8*)&Bl[off];
        }
#pragma unroll
        for (int mi = 0; mi < 4; ++mi)
#pragma unroll
            for (int ni = 0; ni < 4; ++ni) {
                acc[mi][ni] = __builtin_amdgcn_mfma_f32_16x16x32_bf16(ah[mi], bh[ni], acc[mi][ni], 0, 0, 0);
                acc[mi][ni] = __builtin_amdgcn_mfma_f32_16x16x32_bf16(ah[mi], bl[ni], acc[mi][ni], 0, 0, 0);
                acc[mi][ni] = __builtin_amdgcn_mfma_f32_16x16x32_bf16(al[mi], bh[ni], acc[mi][ni], 0, 0, 0);
            }
        __syncthreads();
    }

#pragma unroll
    for (int ni = 0; ni < 4; ++ni) {
        const int c = col0 + wn * 64 + ni * 16 + fr;
        const float bv = bias[c];
#pragma unroll
        for (int mi = 0; mi < 4; ++mi) {
            const int r = row0 + wm * 64 + mi * 16 + s4 * 4;
#pragma unroll
            for (int q = 0; q < 4; ++q)
                C[(size_t)(r + q) * Nd + c] = acc[mi][ni][q] + bv;
        }
    }
}

// ---------------- scalars ----------------
__global__ __launch_bounds__(512)
void finalize_scalars(const unsigned* __restrict__ counts,
                      const float* __restrict__ loss_sum, float* __restrict__ out5) {
    __shared__ float rent[512];
    __shared__ float ruse[512];
    int t = threadIdx.x;
    float c = (float)counts[t];
    float avg = c * (1.0f / (float)NROWS);
    rent[t] = avg * logf(avg + 1e-10f);
    ruse[t] = counts[t] > 0u ? 1.f : 0.f;
    __syncthreads();
    for (int st = 256; st; st >>= 1) {
        if (t < st) { rent[t] += rent[t + st]; ruse[t] += ruse[t + st]; }
        __syncthreads();
    }
    if (t == 0) {
        float H = -rent[0];
        float perp = expf(H);
        float cl = loss_sum[0] * (1.0f / (float)NELEM);
        out5[0] = cl + 0.25f * cl;
        out5[1] = cl;
        out5[2] = cl;
        out5[3] = perp;
        out5[4] = ruse[0] * (1.0f / (float)NCODES);
    }
}

extern "C" void kernel_launch(void* const* d_in, const int* in_sizes, int n_in,
                              void* d_out, int out_size, void* d_ws, size_t ws_size,
                              hipStream_t stream) {
    const float* h     = (const float*)d_in[0];
    const float* enc_w = (const float*)d_in[1];
    const float* enc_b = (const float*)d_in[2];
    const float* cb    = (const float*)d_in[3];
    const float* dec_w = (const float*)d_in[4];
    const float* dec_b = (const float*)d_in[5];
    float* out = (float*)d_out;

    float* ws = (float*)d_ws;
    float*    flat     = ws;                         // [0, 16777216)
    float*    xsq      = ws + 16777216;              // 131072 (dead after dist)
    float*    pmin     = ws + 16908288;              // 524288 (dead after finalize)
    int*      pidx     = (int*)(ws + 17432576);      // 524288 (dead after finalize)
    int*      idx_int  = (int*)(ws + 17956864);      // 131072
    float*    esq      = ws + 18087936;              // 512
    unsigned* counts   = (unsigned*)(ws + 18088448); // 512
    float*    loss_sum = ws + 18088960;              // 1

    // overlays (used only after their hosts are dead):
    ushort* Qh  = (ushort*)ws;                       // over flat
    ushort* Ql  = (ushort*)(ws + 8388608);           // over flat
    ushort* cbh = (ushort*)(ws + 16777216);          // over xsq
    ushort* cbl = (ushort*)(ws + 16809984);          // over xsq
    ushort* Wh  = (ushort*)(ws + 16842752);          // over xsq/pmin
    ushort* Wl  = (ushort*)(ws + 17367040);          // over pmin/pidx

    float* msg_out = out;                     // 67108864
    float* idx_out = out + 67108864;          // 131072
    float* sc_out  = out + 67108864 + 131072; // 5

    zero_kernel<<<1, 512, 0, stream>>>(counts, loss_sum);
    sq_pairwise<<<NCODES / 32, 256, 0, stream>>>(cb, esq, NCODES);

    // encoder: flat = h @ enc_w^T + enc_b (numpy kc=384 folds); grid x=col
    gemm_nt2<0, 1, 384><<<dim3(KC_DIM / 128, M_BT / 128), 256, 0, stream>>>(
        h, enc_w, enc_b, flat, M_BT, KC_DIM, D_DIM, nullptr, nullptr, nullptr, nullptr);

    sq_pairwise<<<NROWS / 32, 256, 0, stream>>>(flat, xsq, NROWS);

    // distances + per-colblock argmin; grid x=col
    gemm_nt2<1, 0, 0><<<dim3(NCODES / 128, NROWS / 128), 256, 0, stream>>>(
        flat, cb, nullptr, nullptr, NROWS, NCODES, C_DIM, xsq, esq, pmin, pidx);

    finalize_idx<<<NROWS / 256, 256, 0, stream>>>(pmin, pidx, idx_int, idx_out, counts);

    // xsq/pmin/pidx now dead -> build bf16 splits in their space
    split_hi_lo<<<(NCODES * C_DIM / 4 + 255) / 256, 256, 0, stream>>>(cb, cbh, cbl, NCODES * C_DIM / 4);
    split_hi_lo<<<(D_DIM * KC_DIM / 4 + 255) / 256, 256, 0, stream>>>(dec_w, Wh, Wl, D_DIM * KC_DIM / 4);

    gather_loss<<<NELEM / (256 * 8), 256, 0, stream>>>(flat, idx_int, cb, loss_sum);

    // flat now dead -> gather split-bf16 quantized rows into its space
    build_q<<<NROWS * 16 / 256, 256, 0, stream>>>(idx_int, cbh, cbl, Qh, Ql);

    // decoder on matrix cores; grid x=col
    dec_gemm_bf16<<<dim3(D_DIM / 128, M_BT / 128), 256, 0, stream>>>(
        Qh, Ql, Wh, Wl, dec_b, msg_out);

    finalize_scalars<<<1, 512, 0, stream>>>(counts, loss_sum, sc_out);
}

// Round 7
// 1564.727 us; speedup vs baseline: 1.1163x; 1.1024x over previous
//
#include <hip/hip_runtime.h>
#include <hip/hip_bf16.h>

// B=16, T=2048, D=2048, K(msg)=4, C=128, KC=512, CODEBOOK=512
#define M_BT      32768
#define KC_DIM    512
#define D_DIM     2048
#define C_DIM     128
#define NROWS     131072
#define NCODES    512
#define NELEM     16777216   // NROWS*C_DIM

typedef __bf16 bf16x8 __attribute__((ext_vector_type(8)));
typedef float  f32x4  __attribute__((ext_vector_type(4)));

#define AS3(p) ((__attribute__((address_space(3))) void*)(p))
#define AS1(p) ((const __attribute__((address_space(1))) void*)(p))

static __device__ __forceinline__ ushort f2bf(float x) {
    unsigned u = __float_as_uint(x);
    unsigned r = (u + 0x7fffu + ((u >> 16) & 1u)) >> 16;
    return (ushort)r;
}
static __device__ __forceinline__ float bf2f(ushort u) {
    return __uint_as_float(((unsigned)u) << 16);
}

// ---------------- zero counters ----------------
__global__ __launch_bounds__(512)
void zero_kernel(unsigned* __restrict__ counts, float* __restrict__ loss_sum) {
    counts[threadIdx.x] = 0u;
    if (threadIdx.x == 0) loss_sum[0] = 0.f;
}

// ---------------- numpy-pairwise sum of squares per 128-row ----------------
__global__ __launch_bounds__(256)
void sq_pairwise(const float* __restrict__ src, float* __restrict__ dst, int nrows) {
    int t = threadIdx.x;
    int row = blockIdx.x * 32 + (t >> 3);
    int j = t & 7;
    if (row >= nrows) return;
    const float* p = src + (size_t)row * C_DIM + j;
    float v = p[0];
    float r = __fmul_rn(v, v);
#pragma unroll
    for (int i = 1; i < 16; ++i) {
        float u = p[i * 8];
        r = __fadd_rn(r, __fmul_rn(u, u));
    }
    r = __fadd_rn(r, __shfl_xor(r, 1));
    r = __fadd_rn(r, __shfl_xor(r, 2));
    r = __fadd_rn(r, __shfl_xor(r, 4));
    if (j == 0) dst[row] = r;
}

// ---------------- encoder GEMM: 128x64 tile, 8x4 micro, kc=384 folds ----------------
// flat = h @ enc_w^T + enc_b. 1-D grid with XCD swizzle: 8 col-blocks sharing an
// A-row-tile run on the same XCD. Per-element FMA order identical to r3 (bit-exact).
__global__ __launch_bounds__(256, 2)
void enc_gemm(const float* __restrict__ A, const float* __restrict__ B,
              const float* __restrict__ bias, float* __restrict__ C)
{
    constexpr int K = D_DIM, N = KC_DIM;
    __shared__ float As[4096];   // 128 rows x 32 k
    __shared__ float Bs[2048];   // 64 rows x 32 k
    const int gid = blockIdx.x;                       // 2048 blocks
    const int f   = (gid & 7) * 256 + (gid >> 3);     // XCD-contiguous
    const int bx  = f & 7, by = f >> 3;
    const int row0 = by * 128, col0 = bx * 64;

    const int tid  = threadIdx.x;
    const int ty   = tid >> 4, tx = tid & 15;
    const int lane = tid & 63, wave = tid >> 6;

    float acc[8][4], accC[8][4];
#pragma unroll
    for (int i = 0; i < 8; ++i)
#pragma unroll
        for (int j = 0; j < 4; ++j) { acc[i][j] = 0.f; accC[i][j] = 0.f; }

    // staging bases: A groups g=wave*4+rr (16x8 rows); B groups g=wave*2+rr (8x8 rows)
    const int lr = lane >> 3, lc = lane & 7;
    const int w4 = (wave & 1) * 4;                    // (wave*4)&7
    const size_t arow = (size_t)(row0 + wave * 32 + lr) * K;
    const int    ac0  = lc ^ w4;                      // chunk base, XOR rr per issue
    const size_t brow = (size_t)(col0 + wave * 16 + lr) * K;
    const int    bc0  = lc ^ ((wave * 2) & 7);        // XOR rr (rr in {0,1})

    const int sa = ty & 7, sb = tx >> 1;

    for (int k0 = 0; k0 < K; k0 += 32) {
#pragma unroll
        for (int rr = 0; rr < 4; ++rr)
            __builtin_amdgcn_global_load_lds(AS1(A + arow + (size_t)rr * 8 * K + k0 + ((ac0 ^ rr) << 2)),
                                             AS3(As + (wave * 4 + rr) * 256), 16, 0, 0);
#pragma unroll
        for (int rr = 0; rr < 2; ++rr)
            __builtin_amdgcn_global_load_lds(AS1(B + brow + (size_t)rr * 8 * K + k0 + ((bc0 ^ rr) << 2)),
                                             AS3(Bs + (wave * 2 + rr) * 256), 16, 0, 0);
        __syncthreads();

#pragma unroll
        for (int kk = 0; kk < 8; ++kk) {
            float4 b4[4];
#pragma unroll
            for (int j = 0; j < 4; ++j)
                b4[j] = *(const float4*)&Bs[(tx * 4 + j) * 32 + ((kk ^ sb) << 2)];
#pragma unroll
            for (int i = 0; i < 8; ++i) {
                float4 a4 = *(const float4*)&As[(ty * 8 + i) * 32 + ((kk ^ sa) << 2)];
#pragma unroll
                for (int j = 0; j < 4; ++j) {
                    float t = accC[i][j];
                    t = fmaf(a4.x, b4[j].x, t);
                    t = fmaf(a4.y, b4[j].y, t);
                    t = fmaf(a4.z, b4[j].z, t);
                    t = fmaf(a4.w, b4[j].w, t);
                    accC[i][j] = t;
                }
            }
        }
        __syncthreads();

        if (((k0 + 32) % 384) == 0) {
#pragma unroll
            for (int i = 0; i < 8; ++i)
#pragma unroll
                for (int j = 0; j < 4; ++j) {
                    acc[i][j] = __fadd_rn(acc[i][j], accC[i][j]);
                    accC[i][j] = 0.f;
                }
        }
    }
    // K=2048 % 384 != 0 -> fold remainder
#pragma unroll
    for (int i = 0; i < 8; ++i)
#pragma unroll
        for (int j = 0; j < 4; ++j)
            acc[i][j] = __fadd_rn(acc[i][j], accC[i][j]);

    float bv[4];
#pragma unroll
    for (int j = 0; j < 4; ++j) bv[j] = bias[col0 + tx * 4 + j];
#pragma unroll
    for (int i = 0; i < 8; ++i) {
        size_t r = (size_t)(row0 + ty * 8 + i) * N + col0 + tx * 4;
        float4 o;
        o.x = __fadd_rn(acc[i][0], bv[0]); o.y = __fadd_rn(acc[i][1], bv[1]);
        o.z = __fadd_rn(acc[i][2], bv[2]); o.w = __fadd_rn(acc[i][3], bv[3]);
        *(float4*)(C + r) = o;
    }
}

// ---------------- dist GEMM (unchanged from r6): 128x128, 8x8, CHUNK=0 ----------------
template<int EPI, int DO_BIAS, int CHUNK>
__global__ __launch_bounds__(256)
void gemm_nt2(const float* __restrict__ A, const float* __restrict__ B,
              const float* __restrict__ bias, float* __restrict__ C,
              int M, int N, int K,
              const float* __restrict__ xsq, const float* __restrict__ esq,
              float* __restrict__ pmin, int* __restrict__ pidx)
{
    __shared__ float As[4096];
    __shared__ float Bs[4096];
    const int tid  = threadIdx.x;
    const int ty   = tid >> 4, tx = tid & 15;
    const int lane = tid & 63, wave = tid >> 6;
    const int row0 = blockIdx.y * 128, col0 = blockIdx.x * 128;

    float acc[8][8];
    float accC[8][8];
#pragma unroll
    for (int i = 0; i < 8; ++i)
#pragma unroll
        for (int j = 0; j < 8; ++j) { acc[i][j] = 0.f; accC[i][j] = 0.f; }

    size_t aoff[4], boff[4];
    int lb[4];
#pragma unroll
    for (int rr = 0; rr < 4; ++rr) {
        const int g = wave * 4 + rr;
        const int r = g * 8 + (lane >> 3);
        const int c = (lane & 7) ^ (g & 7);
        aoff[rr] = (size_t)(row0 + r) * K + c * 4;
        boff[rr] = (size_t)(col0 + r) * K + c * 4;
        lb[rr]   = g * 256;
    }

    const int sa = ty & 7, sb = tx & 7;

    for (int k0 = 0; k0 < K; k0 += 32) {
#pragma unroll
        for (int rr = 0; rr < 4; ++rr) {
            __builtin_amdgcn_global_load_lds(AS1(A + aoff[rr] + k0), AS3(As + lb[rr]), 16, 0, 0);
            __builtin_amdgcn_global_load_lds(AS1(B + boff[rr] + k0), AS3(Bs + lb[rr]), 16, 0, 0);
        }
        __syncthreads();

#pragma unroll
        for (int kk = 0; kk < 8; ++kk) {
            float4 b4[8];
#pragma unroll
            for (int j = 0; j < 8; ++j)
                b4[j] = *(const float4*)&Bs[(tx * 8 + j) * 32 + ((kk ^ sb) << 2)];
#pragma unroll
            for (int i = 0; i < 8; ++i) {
                float4 a4 = *(const float4*)&As[(ty * 8 + i) * 32 + ((kk ^ sa) << 2)];
#pragma unroll
                for (int j = 0; j < 8; ++j) {
                    float t = acc[i][j];
                    t = fmaf(a4.x, b4[j].x, t);
                    t = fmaf(a4.y, b4[j].y, t);
                    t = fmaf(a4.z, b4[j].z, t);
                    t = fmaf(a4.w, b4[j].w, t);
                    acc[i][j] = t;
                }
            }
        }
        __syncthreads();
    }

    if constexpr (EPI == 0) {
        float bv[8];
#pragma unroll
        for (int j = 0; j < 8; ++j) bv[j] = DO_BIAS ? bias[col0 + tx * 8 + j] : 0.f;
#pragma unroll
        for (int i = 0; i < 8; ++i) {
            size_t r = (size_t)(row0 + ty * 8 + i) * N + col0 + tx * 8;
            float4 o0, o1;
            o0.x = __fadd_rn(acc[i][0], bv[0]); o0.y = __fadd_rn(acc[i][1], bv[1]);
            o0.z = __fadd_rn(acc[i][2], bv[2]); o0.w = __fadd_rn(acc[i][3], bv[3]);
            o1.x = __fadd_rn(acc[i][4], bv[4]); o1.y = __fadd_rn(acc[i][5], bv[5]);
            o1.z = __fadd_rn(acc[i][6], bv[6]); o1.w = __fadd_rn(acc[i][7], bv[7]);
            *(float4*)(C + r) = o0;
            *(float4*)(C + r + 4) = o1;
        }
    } else {
        float (*rmin)[16] = (float (*)[16])As;
        int   (*ridx)[16] = (int (*)[16])Bs;
        float es[8];
#pragma unroll
        for (int j = 0; j < 8; ++j) es[j] = esq[col0 + tx * 8 + j];
#pragma unroll
        for (int i = 0; i < 8; ++i) {
            float xs = xsq[row0 + ty * 8 + i];
            float b = __fadd_rn(__fsub_rn(xs, __fmul_rn(2.0f, acc[i][0])), es[0]);
            int bi = col0 + tx * 8;
#pragma unroll
            for (int j = 1; j < 8; ++j) {
                float d = __fadd_rn(__fsub_rn(xs, __fmul_rn(2.0f, acc[i][j])), es[j]);
                if (d < b) { b = d; bi = col0 + tx * 8 + j; }
            }
            rmin[ty * 8 + i][tx] = b;
            ridx[ty * 8 + i][tx] = bi;
        }
        __syncthreads();
        if (tid < 128) {
            float b = rmin[tid][0]; int ix = ridx[tid][0];
#pragma unroll
            for (int t = 1; t < 16; ++t) {
                if (rmin[tid][t] < b) { b = rmin[tid][t]; ix = ridx[tid][t]; }
            }
            size_t o = (size_t)(row0 + tid) * gridDim.x + blockIdx.x;
            pmin[o] = b; pidx[o] = ix;
        }
    }
}

// ---------------- merge 4 col-blocks -> final idx + histogram ----------------
__global__ __launch_bounds__(256)
void finalize_idx(const float* __restrict__ pmin, const int* __restrict__ pidx,
                  int* __restrict__ idx_int, float* __restrict__ idx_f,
                  unsigned* __restrict__ counts) {
    __shared__ unsigned hist[NCODES];
    int t = threadIdx.x;
    hist[t] = 0u; hist[t + 256] = 0u;
    __syncthreads();
    int row = blockIdx.x * 256 + t;
    size_t base = (size_t)row * 4;
    float b = pmin[base]; int ix = pidx[base];
#pragma unroll
    for (int nb = 1; nb < 4; ++nb) {
        float v = pmin[base + nb];
        if (v < b) { b = v; ix = pidx[base + nb]; }
    }
    idx_int[row] = ix;
    idx_f[row] = (float)ix;
    atomicAdd(&hist[ix], 1u);
    __syncthreads();
    if (hist[t]) atomicAdd(&counts[t], hist[t]);
    if (hist[t + 256]) atomicAdd(&counts[t + 256], hist[t + 256]);
}

// ---------------- split codebook / dec_w into bf16 hi+lo ----------------
__global__ __launch_bounds__(256)
void split_hi_lo(const float* __restrict__ src, ushort* __restrict__ hi,
                 ushort* __restrict__ lo, int n4) {
    int e = blockIdx.x * 256 + threadIdx.x;
    if (e >= n4) return;
    float4 v = *(const float4*)&src[(size_t)e * 4];
    ushort h0 = f2bf(v.x), h1 = f2bf(v.y), h2 = f2bf(v.z), h3 = f2bf(v.w);
    ushort l0 = f2bf(v.x - bf2f(h0)), l1 = f2bf(v.y - bf2f(h1));
    ushort l2 = f2bf(v.z - bf2f(h2)), l3 = f2bf(v.w - bf2f(h3));
    ushort4 H; H.x = h0; H.y = h1; H.z = h2; H.w = h3;
    ushort4 L; L.x = l0; L.y = l1; L.z = l2; L.w = l3;
    *(ushort4*)&hi[(size_t)e * 4] = H;
    *(ushort4*)&lo[(size_t)e * 4] = L;
}

// ---------------- loss only (reads flat, does NOT modify it) ----------------
__global__ __launch_bounds__(256)
void gather_loss(const float* __restrict__ flat, const int* __restrict__ idx,
                 const float* __restrict__ cb, float* __restrict__ loss_sum) {
    size_t e0 = ((size_t)blockIdx.x * 256 + threadIdx.x) * 8;
    int n = (int)(e0 >> 7);
    int c = (int)(e0 & 127);
    int k = idx[n];
    const float4* qp = (const float4*)(cb + (size_t)k * C_DIM + c);
    float4 q0 = qp[0], q1 = qp[1];
    const float4* fp = (const float4*)(flat + e0);
    float4 f0 = fp[0], f1 = fp[1];
    float s = 0.f, d;
    d = q0.x - f0.x; s += d * d;  d = q0.y - f0.y; s += d * d;
    d = q0.z - f0.z; s += d * d;  d = q0.w - f0.w; s += d * d;
    d = q1.x - f1.x; s += d * d;  d = q1.y - f1.y; s += d * d;
    d = q1.z - f1.z; s += d * d;  d = q1.w - f1.w; s += d * d;

    __shared__ float redf[256];
    redf[threadIdx.x] = s;
    __syncthreads();
    for (int st = 128; st; st >>= 1) {
        if (threadIdx.x < st) redf[threadIdx.x] += redf[threadIdx.x + st];
        __syncthreads();
    }
    if (threadIdx.x == 0) atomicAdd(loss_sum, redf[0]);
}

// ---------------- gather split-bf16 quantized rows ----------------
__global__ __launch_bounds__(256)
void build_q(const int* __restrict__ idx, const ushort* __restrict__ cbh,
             const ushort* __restrict__ cbl, ushort* __restrict__ Qh,
             ushort* __restrict__ Ql) {
    int t = blockIdx.x * 256 + threadIdx.x;   // 16B chunk id
    int n = t >> 4, c8 = t & 15;
    int k = idx[n];
    uint4 vh = *(const uint4*)&cbh[(size_t)k * C_DIM + c8 * 8];
    uint4 vl = *(const uint4*)&cbl[(size_t)k * C_DIM + c8 * 8];
    *(uint4*)&Qh[(size_t)n * C_DIM + c8 * 8] = vh;
    *(uint4*)&Ql[(size_t)n * C_DIM + c8 * 8] = vl;
}

// ---------------- decoder: split-bf16 MFMA GEMM, XCD-swizzled 1-D grid ----------------
__global__ __launch_bounds__(256)
void dec_gemm_bf16(const ushort* __restrict__ Qh, const ushort* __restrict__ Ql,
                   const ushort* __restrict__ Wh, const ushort* __restrict__ Wl,
                   const float* __restrict__ bias, float* __restrict__ C)
{
    constexpr int Kd = 512, Nd = 2048;
    __shared__ ushort Ah[128 * 32], Al[128 * 32], Bh[128 * 32], Bl[128 * 32];
    const int gid = blockIdx.x;                       // 4096 blocks
    const int f   = (gid & 7) * 512 + (gid >> 3);
    const int bx  = f & 15, by = f >> 4;
    const int tid  = threadIdx.x;
    const int lane = tid & 63, wave = tid >> 6;
    const int wm = wave >> 1, wn = wave & 1;
    const int row0 = by * 128, col0 = bx * 128;

    f32x4 acc[4][4];
#pragma unroll
    for (int i = 0; i < 4; ++i)
#pragma unroll
        for (int j = 0; j < 4; ++j)
#pragma unroll
            for (int q = 0; q < 4; ++q) acc[i][j][q] = 0.f;

    const int fr = lane & 15, s4 = lane >> 4;

    for (int kt = 0; kt < Kd / 32; ++kt) {
        const int k0 = kt * 32;
#pragma unroll
        for (int r = 0; r < 2; ++r) {
            const int t2 = r * 256 + wave * 64 + lane;
            const int ro = t2 >> 2, sb = t2 & 3;
            const int base = (r * 256 + wave * 64) * 8;
            const size_t ga = (size_t)(row0 + ro) * Kd + k0 + sb * 8;
            const size_t gb = (size_t)(col0 + ro) * Kd + k0 + sb * 8;
            __builtin_amdgcn_global_load_lds(AS1(Qh + ga), AS3(&Ah[base]), 16, 0, 0);
            __builtin_amdgcn_global_load_lds(AS1(Ql + ga), AS3(&Al[base]), 16, 0, 0);
            __builtin_amdgcn_global_load_lds(AS1(Wh + gb), AS3(&Bh[base]), 16, 0, 0);
            __builtin_amdgcn_global_load_lds(AS1(Wl + gb), AS3(&Bl[base]), 16, 0, 0);
        }
        __syncthreads();

        bf16x8 ah[4], al[4], bh[4], bl[4];
#pragma unroll
        for (int mi = 0; mi < 4; ++mi) {
            const int off = (wm * 64 + mi * 16 + fr) * 32 + s4 * 8;
            ah[mi] = *(const bf16x8*)&Ah[off];
            al[mi] = *(const bf16x8*)&Al[off];
        }
#pragma unroll
        for (int ni = 0; ni < 4; ++ni) {
            const int off = (wn * 64 + ni * 16 + fr) * 32 + s4 * 8;
            bh[ni] = *(const bf16x8*)&Bh[off];
            bl[ni] = *(const bf16x8*)&Bl[off];
        }
#pragma unroll
        for (int mi = 0; mi < 4; ++mi)
#pragma unroll
            for (int ni = 0; ni < 4; ++ni) {
                acc[mi][ni] = __builtin_amdgcn_mfma_f32_16x16x32_bf16(ah[mi], bh[ni], acc[mi][ni], 0, 0, 0);
                acc[mi][ni] = __builtin_amdgcn_mfma_f32_16x16x32_bf16(ah[mi], bl[ni], acc[mi][ni], 0, 0, 0);
                acc[mi][ni] = __builtin_amdgcn_mfma_f32_16x16x32_bf16(al[mi], bh[ni], acc[mi][ni], 0, 0, 0);
            }
        __syncthreads();
    }

#pragma unroll
    for (int ni = 0; ni < 4; ++ni) {
        const int c = col0 + wn * 64 + ni * 16 + fr;
        const float bv = bias[c];
#pragma unroll
        for (int mi = 0; mi < 4; ++mi) {
            const int r = row0 + wm * 64 + mi * 16 + s4 * 4;
#pragma unroll
            for (int q = 0; q < 4; ++q)
                C[(size_t)(r + q) * Nd + c] = acc[mi][ni][q] + bv;
        }
    }
}

// ---------------- scalars ----------------
__global__ __launch_bounds__(512)
void finalize_scalars(const unsigned* __restrict__ counts,
                      const float* __restrict__ loss_sum, float* __restrict__ out5) {
    __shared__ float rent[512];
    __shared__ float ruse[512];
    int t = threadIdx.x;
    float c = (float)counts[t];
    float avg = c * (1.0f / (float)NROWS);
    rent[t] = avg * logf(avg + 1e-10f);
    ruse[t] = counts[t] > 0u ? 1.f : 0.f;
    __syncthreads();
    for (int st = 256; st; st >>= 1) {
        if (t < st) { rent[t] += rent[t + st]; ruse[t] += ruse[t + st]; }
        __syncthreads();
    }
    if (t == 0) {
        float H = -rent[0];
        float perp = expf(H);
        float cl = loss_sum[0] * (1.0f / (float)NELEM);
        out5[0] = cl + 0.25f * cl;
        out5[1] = cl;
        out5[2] = cl;
        out5[3] = perp;
        out5[4] = ruse[0] * (1.0f / (float)NCODES);
    }
}

extern "C" void kernel_launch(void* const* d_in, const int* in_sizes, int n_in,
                              void* d_out, int out_size, void* d_ws, size_t ws_size,
                              hipStream_t stream) {
    const float* h     = (const float*)d_in[0];
    const float* enc_w = (const float*)d_in[1];
    const float* enc_b = (const float*)d_in[2];
    const float* cb    = (const float*)d_in[3];
    const float* dec_w = (const float*)d_in[4];
    const float* dec_b = (const float*)d_in[5];
    float* out = (float*)d_out;

    float* ws = (float*)d_ws;
    float*    flat     = ws;                         // [0, 16777216)
    float*    xsq      = ws + 16777216;              // 131072 (dead after dist)
    float*    pmin     = ws + 16908288;              // 524288 (dead after finalize)
    int*      pidx     = (int*)(ws + 17432576);      // 524288 (dead after finalize)
    int*      idx_int  = (int*)(ws + 17956864);      // 131072
    float*    esq      = ws + 18087936;              // 512
    unsigned* counts   = (unsigned*)(ws + 18088448); // 512
    float*    loss_sum = ws + 18088960;              // 1

    // overlays (used only after their hosts are dead):
    ushort* Qh  = (ushort*)ws;                       // over flat
    ushort* Ql  = (ushort*)(ws + 8388608);           // over flat
    ushort* cbh = (ushort*)(ws + 16777216);          // over xsq
    ushort* cbl = (ushort*)(ws + 16809984);          // over xsq
    ushort* Wh  = (ushort*)(ws + 16842752);          // over xsq/pmin
    ushort* Wl  = (ushort*)(ws + 17367040);          // over pmin/pidx

    float* msg_out = out;                     // 67108864
    float* idx_out = out + 67108864;          // 131072
    float* sc_out  = out + 67108864 + 131072; // 5

    zero_kernel<<<1, 512, 0, stream>>>(counts, loss_sum);
    sq_pairwise<<<NCODES / 32, 256, 0, stream>>>(cb, esq, NCODES);

    // encoder: flat = h @ enc_w^T + enc_b (numpy kc=384 folds), 128x64 tiles, XCD-swizzled
    enc_gemm<<<2048, 256, 0, stream>>>(h, enc_w, enc_b, flat);

    sq_pairwise<<<NROWS / 32, 256, 0, stream>>>(flat, xsq, NROWS);

    // distances + per-colblock argmin (unchanged r6 structure)
    gemm_nt2<1, 0, 0><<<dim3(NCODES / 128, NROWS / 128), 256, 0, stream>>>(
        flat, cb, nullptr, nullptr, NROWS, NCODES, C_DIM, xsq, esq, pmin, pidx);

    finalize_idx<<<NROWS / 256, 256, 0, stream>>>(pmin, pidx, idx_int, idx_out, counts);

    // xsq/pmin/pidx now dead -> build bf16 splits in their space
    split_hi_lo<<<(NCODES * C_DIM / 4 + 255) / 256, 256, 0, stream>>>(cb, cbh, cbl, NCODES * C_DIM / 4);
    split_hi_lo<<<(D_DIM * KC_DIM / 4 + 255) / 256, 256, 0, stream>>>(dec_w, Wh, Wl, D_DIM * KC_DIM / 4);

    gather_loss<<<NELEM / (256 * 8), 256, 0, stream>>>(flat, idx_int, cb, loss_sum);

    // flat now dead -> gather split-bf16 quantized rows into its space
    build_q<<<NROWS * 16 / 256, 256, 0, stream>>>(idx_int, cbh, cbl, Qh, Ql);

    // decoder on matrix cores, XCD-swizzled
    dec_gemm_bf16<<<4096, 256, 0, stream>>>(Qh, Ql, Wh, Wl, dec_b, msg_out);

    finalize_scalars<<<1, 512, 0, stream>>>(counts, loss_sum, sc_out);
}